// Round 15
// baseline (283.502 us; speedup 1.0000x reference)
//
#include <hip/hip_runtime.h>
#include <math.h>

#define RAD 20
#define KLEN 41
#define NH 1024
#define NW 2048
#define NHW (NH * NW)

// ---- Compile-time Gaussian-derivative weights (fp64, matches numpy) ----
struct KW { float w[KLEN]; };
constexpr double cexp_neg(double u) {  // exp(-u), 0 <= u <= 0.5
  double term = 1.0, sum = 1.0;
  for (int k = 1; k < 30; ++k) { term *= (-u) / (double)k; sum += term; }
  return sum;
}
constexpr KW make_kw() {
  KW r{};
  double ph[KLEN] = {};
  double s = 0.0;
  for (int i = 0; i < KLEN; ++i) {
    double d = (double)(i - RAD);
    double e = cexp_neg(d * d / 800.0);
    e = e * e; e = e * e; e = e * e; e = e * e;  // ^16
    ph[i] = e; s += e;
  }
  for (int i = 0; i < KLEN; ++i) {
    double d = (double)(i - RAD);
    r.w[i] = (float)((-d / 25.0) * (ph[i] / s) / 2.27);
  }
  return r;
}
static constexpr KW KWC = make_kw();

// Tap-major conv core, 8-accumulator form.
template <int K>
__device__ __forceinline__ void tap(float s, float& r0, float& r1, float& r2,
                                    float& r3, float& r4, float& r5, float& r6,
                                    float& r7) {
  if constexpr (K - 0 >= 0 && K - 0 <= 40) r0 = fmaf(s, KWC.w[K - 0], r0);
  if constexpr (K - 1 >= 0 && K - 1 <= 40) r1 = fmaf(s, KWC.w[K - 1], r1);
  if constexpr (K - 2 >= 0 && K - 2 <= 40) r2 = fmaf(s, KWC.w[K - 2], r2);
  if constexpr (K - 3 >= 0 && K - 3 <= 40) r3 = fmaf(s, KWC.w[K - 3], r3);
  if constexpr (K - 4 >= 0 && K - 4 <= 40) r4 = fmaf(s, KWC.w[K - 4], r4);
  if constexpr (K - 5 >= 0 && K - 5 <= 40) r5 = fmaf(s, KWC.w[K - 5], r5);
  if constexpr (K - 6 >= 0 && K - 6 <= 40) r6 = fmaf(s, KWC.w[K - 6], r6);
  if constexpr (K - 7 >= 0 && K - 7 <= 40) r7 = fmaf(s, KWC.w[K - 7], r7);
}

#define R8 r0, r1, r2, r3, r4, r5, r6, r7

#define TW 64  // k_dyf tile width (x)
#define TH 64  // k_dyf output rows per block
#define TILE_CH ((TH + 2 * RAD) * TW)  // 104*64 = 6656 floats per channel slot

// Column conv along y within a staged channel tile (same chunk/tap order as
// the original k_dy -> bit-identical dY results).
__device__ __forceinline__ void conv_col(const float* __restrict__ t, int base,
                                         int lane, float& r0, float& r1,
                                         float& r2, float& r3, float& r4,
                                         float& r5, float& r6, float& r7) {
#define CCHUNK(c)                                      \
  {                                                    \
    float s0 = t[(base + 4 * (c) + 0) * TW + lane];    \
    float s1 = t[(base + 4 * (c) + 1) * TW + lane];    \
    float s2 = t[(base + 4 * (c) + 2) * TW + lane];    \
    float s3 = t[(base + 4 * (c) + 3) * TW + lane];    \
    tap<4 * (c) + 0>(s0, R8);                          \
    tap<4 * (c) + 1>(s1, R8);                          \
    tap<4 * (c) + 2>(s2, R8);                          \
    tap<4 * (c) + 3>(s3, R8);                          \
  }
  CCHUNK(0) CCHUNK(1) CCHUNK(2) CCHUNK(3) CCHUNK(4) CCHUNK(5)
  CCHUNK(6) CCHUNK(7) CCHUNK(8) CCHUNK(9) CCHUNK(10) CCHUNK(11)
#undef CCHUNK
}

__device__ __forceinline__ int reflx(int x) {
  int xr = x < 0 ? -x : x;
  return xr > NW - 1 ? 2 * NW - 2 - xr : xr;
}

// diffX, LDS-free (round-15): each thread's window is 48 ROW-CONTIGUOUS
// floats at xs=8t-20 (16B-aligned) -> 12 direct float4 global loads for
// interior threads (lane overlap = same cache lines, same wave-instr; L1
// serves it -- unlike round-10's cross-row k_dyf failure). No LDS, no
// barrier, no staging, no swizzle. Edge threads (t<3, t>252) take scalar
// reflected loads. Same values, same tap order -> dX bit-identical.
// ch==0 blocks also accumulate sum ||m||_F (plane-0 row values are already
// in regs: w20..w27 = rp[8t..8t+7]).
__global__ __launch_bounds__(256, 4) void k_dx(const float* __restrict__ y,
                                               const float* __restrict__ v,
                                               float* __restrict__ ws,
                                               double* __restrict__ acc) {
  __shared__ double rsm[4];
  const int t = threadIdx.x;
  const int lane = t & 63;
  const int wid = t >> 6;
  const int r = blockIdx.x;
  const int ch = blockIdx.y;  // 0..6 -> y0..y4, v0, v1
  const float* src = (ch < 5) ? (y + (size_t)ch * NHW) : (v + (size_t)(ch - 5) * NHW);
  const float* rp = src + (size_t)r * NW;

  const int xb = 8 * t;
  const int xs = xb - RAD;  // 16B-aligned (8t-20 ≡ 0 mod 4)

  float w0, w1, w2, w3, w4, w5, w6, w7, w8, w9, w10, w11;
  float w12, w13, w14, w15, w16, w17, w18, w19, w20, w21, w22, w23;
  float w24, w25, w26, w27, w28, w29, w30, w31, w32, w33, w34, w35;
  float w36, w37, w38, w39, w40, w41, w42, w43, w44, w45, w46, w47;

  if (t >= 3 && t <= 252) {  // interior: window fully in-bounds
    const float4* p = (const float4*)(rp + xs);
    float4 f0 = p[0], f1 = p[1], f2 = p[2], f3 = p[3];
    float4 f4 = p[4], f5 = p[5], f6 = p[6], f7 = p[7];
    float4 f8 = p[8], f9 = p[9], f10 = p[10], f11 = p[11];
    w0 = f0.x; w1 = f0.y; w2 = f0.z; w3 = f0.w;
    w4 = f1.x; w5 = f1.y; w6 = f1.z; w7 = f1.w;
    w8 = f2.x; w9 = f2.y; w10 = f2.z; w11 = f2.w;
    w12 = f3.x; w13 = f3.y; w14 = f3.z; w15 = f3.w;
    w16 = f4.x; w17 = f4.y; w18 = f4.z; w19 = f4.w;
    w20 = f5.x; w21 = f5.y; w22 = f5.z; w23 = f5.w;
    w24 = f6.x; w25 = f6.y; w26 = f6.z; w27 = f6.w;
    w28 = f7.x; w29 = f7.y; w30 = f7.z; w31 = f7.w;
    w32 = f8.x; w33 = f8.y; w34 = f8.z; w35 = f8.w;
    w36 = f9.x; w37 = f9.y; w38 = f9.z; w39 = f9.w;
    w40 = f10.x; w41 = f10.y; w42 = f10.z; w43 = f10.w;
    w44 = f11.x; w45 = f11.y; w46 = f11.z; w47 = f11.w;
  } else {  // edge: scalar reflected loads (6 threads per block)
    w0 = rp[reflx(xs + 0)]; w1 = rp[reflx(xs + 1)]; w2 = rp[reflx(xs + 2)];
    w3 = rp[reflx(xs + 3)]; w4 = rp[reflx(xs + 4)]; w5 = rp[reflx(xs + 5)];
    w6 = rp[reflx(xs + 6)]; w7 = rp[reflx(xs + 7)]; w8 = rp[reflx(xs + 8)];
    w9 = rp[reflx(xs + 9)]; w10 = rp[reflx(xs + 10)]; w11 = rp[reflx(xs + 11)];
    w12 = rp[reflx(xs + 12)]; w13 = rp[reflx(xs + 13)]; w14 = rp[reflx(xs + 14)];
    w15 = rp[reflx(xs + 15)]; w16 = rp[reflx(xs + 16)]; w17 = rp[reflx(xs + 17)];
    w18 = rp[reflx(xs + 18)]; w19 = rp[reflx(xs + 19)]; w20 = rp[reflx(xs + 20)];
    w21 = rp[reflx(xs + 21)]; w22 = rp[reflx(xs + 22)]; w23 = rp[reflx(xs + 23)];
    w24 = rp[reflx(xs + 24)]; w25 = rp[reflx(xs + 25)]; w26 = rp[reflx(xs + 26)];
    w27 = rp[reflx(xs + 27)]; w28 = rp[reflx(xs + 28)]; w29 = rp[reflx(xs + 29)];
    w30 = rp[reflx(xs + 30)]; w31 = rp[reflx(xs + 31)]; w32 = rp[reflx(xs + 32)];
    w33 = rp[reflx(xs + 33)]; w34 = rp[reflx(xs + 34)]; w35 = rp[reflx(xs + 35)];
    w36 = rp[reflx(xs + 36)]; w37 = rp[reflx(xs + 37)]; w38 = rp[reflx(xs + 38)];
    w39 = rp[reflx(xs + 39)]; w40 = rp[reflx(xs + 40)]; w41 = rp[reflx(xs + 41)];
    w42 = rp[reflx(xs + 42)]; w43 = rp[reflx(xs + 43)]; w44 = rp[reflx(xs + 44)];
    w45 = rp[reflx(xs + 45)]; w46 = rp[reflx(xs + 46)]; w47 = rp[reflx(xs + 47)];
  }

  float r0 = 0.f, r1 = 0.f, r2 = 0.f, r3 = 0.f;
  float r4 = 0.f, r5 = 0.f, r6 = 0.f, r7 = 0.f;
#define TAPW(k) tap<k>(w##k, R8);
  TAPW(0)  TAPW(1)  TAPW(2)  TAPW(3)  TAPW(4)  TAPW(5)  TAPW(6)  TAPW(7)
  TAPW(8)  TAPW(9)  TAPW(10) TAPW(11) TAPW(12) TAPW(13) TAPW(14) TAPW(15)
  TAPW(16) TAPW(17) TAPW(18) TAPW(19) TAPW(20) TAPW(21) TAPW(22) TAPW(23)
  TAPW(24) TAPW(25) TAPW(26) TAPW(27) TAPW(28) TAPW(29) TAPW(30) TAPW(31)
  TAPW(32) TAPW(33) TAPW(34) TAPW(35) TAPW(36) TAPW(37) TAPW(38) TAPW(39)
  TAPW(40) TAPW(41) TAPW(42) TAPW(43) TAPW(44) TAPW(45) TAPW(46) TAPW(47)
#undef TAPW

  float4 o0, o1;
  o0.x = r0; o0.y = r1; o0.z = r2; o0.w = r3;
  o1.x = r4; o1.y = r5; o1.z = r6; o1.w = r7;
  float4* dst = (float4*)(ws + (size_t)(7 + ch) * NHW + (size_t)r * NW + xb);
  dst[0] = o0;
  dst[1] = o1;

  if (ch == 0) {  // block-uniform: m_0 numerator. Plane 0 = w20..w27 (regs).
    const size_t ro = (size_t)r * NW + xb;
    float4 p1a = *(const float4*)(y + (size_t)NHW + ro);
    float4 p1b = *(const float4*)(y + (size_t)NHW + ro + 4);
    float4 p2a = *(const float4*)(y + 2 * (size_t)NHW + ro);
    float4 p2b = *(const float4*)(y + 2 * (size_t)NHW + ro + 4);
    float4 p3a = *(const float4*)(y + 3 * (size_t)NHW + ro);
    float4 p3b = *(const float4*)(y + 3 * (size_t)NHW + ro + 4);
    double local =
        (double)sqrtf(w20 * w20 + p1a.x * p1a.x + p2a.x * p2a.x + p3a.x * p3a.x) +
        (double)sqrtf(w21 * w21 + p1a.y * p1a.y + p2a.y * p2a.y + p3a.y * p3a.y) +
        (double)sqrtf(w22 * w22 + p1a.z * p1a.z + p2a.z * p2a.z + p3a.z * p3a.z) +
        (double)sqrtf(w23 * w23 + p1a.w * p1a.w + p2a.w * p2a.w + p3a.w * p3a.w) +
        (double)sqrtf(w24 * w24 + p1b.x * p1b.x + p2b.x * p2b.x + p3b.x * p3b.x) +
        (double)sqrtf(w25 * w25 + p1b.y * p1b.y + p2b.y * p2b.y + p3b.y * p3b.y) +
        (double)sqrtf(w26 * w26 + p1b.z * p1b.z + p2b.z * p2b.z + p3b.z * p3b.z) +
        (double)sqrtf(w27 * w27 + p1b.w * p1b.w + p2b.w * p2b.w + p3b.w * p3b.w);
#pragma unroll
    for (int off = 32; off > 0; off >>= 1) local += __shfl_down(local, off, 64);
    if (lane == 0) rsm[wid] = local;
    __syncthreads();
    if (t == 0) atomicAdd(acc, rsm[0] + rsm[1] + rsm[2] + rsm[3]);
  }
}

// ---- Fused diffY + pointwise, 2-slot pipeline, TH=64 (round-14 measured
// 43-45us; unchanged). Staging is the SCALAR named-register pattern --
// round-11 lesson: vector/conditional staging spills the 56 accumulators.
__global__ __launch_bounds__(512, 4) void k_dyf(
    const float* __restrict__ y, const float* __restrict__ v,
    const float* __restrict__ gds, const float* __restrict__ cadc,
    const float* __restrict__ myoc, const float* __restrict__ ws,
    const double* __restrict__ acc, float* __restrict__ out) {
  __shared__ float tile[2 * TILE_CH];  // 53248 B
  const int lane = threadIdx.x & 63;
  const int wid = threadIdx.x >> 6;  // 0..7
  const int x0 = blockIdx.x * TW;
  const int yb = blockIdx.y * TH;
  const int base = wid * 8;

  const float m0 = (float)(acc[0] / (double)NHW);
  const float cad0 = fmaxf(cadc[0], 0.f);
  const float cad1 = fmaxf(cadc[1], 0.f);
  const float cad2 = fmaxf(cadc[2], 0.f);
  const float my0 = fmaxf(myoc[0], 0.f);
  const float my1 = fmaxf(myoc[1], 0.f);
  const float my2 = fmaxf(myoc[2], 0.f);
  const float my3 = fmaxf(myoc[3], 0.f);
  const float my4 = fmaxf(myoc[4], 0.f);

// Wave `wid` stages tile rows wid, wid+8, ..., wid+96 (13 rows).
#define SGLD(sp, k) \
  (sp)[(size_t)(((yb - RAD + wid + 8 * (k)) + NH) & (NH - 1)) * NW + x0 + lane]

  float u0, u1, u2, u3, u4, u5, u6;
  float u7, u8, u9, u10, u11, u12;

#define LOADCH(srcp)                                                   \
  {                                                                    \
    const float* sp_ = (srcp);                                         \
    u0 = SGLD(sp_, 0); u1 = SGLD(sp_, 1); u2 = SGLD(sp_, 2);           \
    u3 = SGLD(sp_, 3); u4 = SGLD(sp_, 4); u5 = SGLD(sp_, 5);           \
    u6 = SGLD(sp_, 6); u7 = SGLD(sp_, 7); u8 = SGLD(sp_, 8);           \
    u9 = SGLD(sp_, 9); u10 = SGLD(sp_, 10); u11 = SGLD(sp_, 11);       \
    u12 = SGLD(sp_, 12);                                               \
  }
#define WRITECH(g)                                                        \
  {                                                                       \
    float* tb_ = &tile[(g) * TILE_CH];                                    \
    tb_[(wid + 0) * TW + lane] = u0;   tb_[(wid + 8) * TW + lane] = u1;   \
    tb_[(wid + 16) * TW + lane] = u2;  tb_[(wid + 24) * TW + lane] = u3;  \
    tb_[(wid + 32) * TW + lane] = u4;  tb_[(wid + 40) * TW + lane] = u5;  \
    tb_[(wid + 48) * TW + lane] = u6;  tb_[(wid + 56) * TW + lane] = u7;  \
    tb_[(wid + 64) * TW + lane] = u8;  tb_[(wid + 72) * TW + lane] = u9;  \
    tb_[(wid + 80) * TW + lane] = u10; tb_[(wid + 88) * TW + lane] = u11; \
    tb_[(wid + 96) * TW + lane] = u12;                                    \
  }
#define DECL8(P)                                                       \
  float P##0 = 0.f, P##1 = 0.f, P##2 = 0.f, P##3 = 0.f, P##4 = 0.f,    \
        P##5 = 0.f, P##6 = 0.f, P##7 = 0.f;
#define CALLCONV(g, P)                                                  \
  conv_col(&tile[(g) * TILE_CH], base, lane, P##0, P##1, P##2, P##3,    \
           P##4, P##5, P##6, P##7);

  DECL8(ym00) DECL8(ym01) DECL8(ym10) DECL8(ym11)
  DECL8(yc) DECL8(yv0) DECL8(yv1)

  // Prologue: stage ch0 (m00) into slot 0.
  LOADCH(y)
  WRITECH(0)
  __syncthreads();
  // Step 0: conv m00 (slot0); prefetch+write m01 -> slot1.
  LOADCH(y + (size_t)NHW)
  CALLCONV(0, ym00)
  WRITECH(1)
  __syncthreads();
  // Step 1: conv m01 (slot1); prefetch+write m10 -> slot0.
  LOADCH(y + 2 * (size_t)NHW)
  CALLCONV(1, ym01)
  WRITECH(0)
  __syncthreads();
  // Step 2: conv m10 (slot0); prefetch+write m11 -> slot1.
  LOADCH(y + 3 * (size_t)NHW)
  CALLCONV(0, ym10)
  WRITECH(1)
  __syncthreads();
  // Step 3: conv m11 (slot1); prefetch+write c -> slot0.
  LOADCH(y + 4 * (size_t)NHW)
  CALLCONV(1, ym11)
  WRITECH(0)
  __syncthreads();
  // Step 4: conv c (slot0); prefetch+write v0 -> slot1.
  LOADCH(v)
  CALLCONV(0, yc)
  WRITECH(1)
  __syncthreads();
  // Step 5: conv v0 (slot1); prefetch+write v1 -> slot0.
  LOADCH(v + (size_t)NHW)
  CALLCONV(1, yv0)
  WRITECH(0)
  __syncthreads();
  // Step 6: conv v1 (slot0). No further staging, no barrier needed.
  CALLCONV(0, yv1)

  // Phase C: pointwise algebra per owned pixel (rows yb+base+q, col x0+lane).
#define POINT(q)                                                              \
  {                                                                           \
    const size_t idx = (size_t)(yb + base + (q)) * NW + x0 + lane;            \
    const float m00 = y[idx];                                                 \
    const float m01 = y[idx + (size_t)NHW];                                   \
    const float m10 = y[idx + 2 * (size_t)NHW];                               \
    const float m11 = y[idx + 3 * (size_t)NHW];                               \
    const float c = y[idx + 4 * (size_t)NHW];                                 \
    const float v0 = v[idx];                                                  \
    const float v1 = v[idx + (size_t)NHW];                                    \
    const float g = gds[idx];                                                 \
    const float dY_m00 = ym00##q, dY_m01 = ym01##q;                           \
    const float dY_m10 = ym10##q, dY_m11 = ym11##q;                           \
    const float dY_c = yc##q, dY_v0 = yv0##q, dY_v1 = yv1##q;                 \
    const float dX_m00 = ws[idx + 7 * (size_t)NHW];                           \
    const float dX_m01 = ws[idx + 8 * (size_t)NHW];                           \
    const float dX_m10 = ws[idx + 9 * (size_t)NHW];                           \
    const float dX_m11 = ws[idx + 10 * (size_t)NHW];                          \
    const float dX_c = ws[idx + 11 * (size_t)NHW];                            \
    const float dX_v0 = ws[idx + 12 * (size_t)NHW];                           \
    const float dX_v1 = ws[idx + 13 * (size_t)NHW];                           \
    const float gv00 = dY_v0, gv01 = dX_v0, gv10 = dY_v1, gv11 = dX_v1;       \
    const float ww = -0.5f * (gv01 - gv10);                                   \
    const float E00 = gv00, E11 = gv11;                                       \
    const float E01 = 0.5f * (gv01 + gv10);                                   \
    const float E10 = E01;                                                    \
    const float trm = m00 + m11;                                              \
    const float dev00 = m00 - 0.5f * trm;                                     \
    const float dev01 = m01;                                                  \
    const float dev10 = m10;                                                  \
    const float dev11 = m11 - 0.5f * trm;                                     \
    const float dmag_sq =                                                     \
        dev00 * dev00 + dev01 * dev01 + dev10 * dev10 + dev11 * dev11;        \
    const float dm = sqrtf(dmag_sq);                                          \
    const float dm2 = dm * dm;                                                \
    const float devE = dev00 * E00 + dev01 * E01 + dev10 * E10 + dev11 * E11; \
    const float sg = (devE > 0.f) ? 1.f : ((devE < 0.f) ? -1.f : 0.f);        \
    const float coef = sg * devE / dm2;                                       \
    const float sc = 0.5f * dm / m0;                                          \
    const float Ea00 = (E00 - coef * dev00) * sc;                             \
    const float Ea01 = (E01 - coef * dev01) * sc;                             \
    const float Ea10 = (E10 - coef * dev10) * sc;                             \
    const float Ea11 = (E11 - coef * dev11) * sc;                             \
    const float Ep00 = E00 - Ea00;                                            \
    const float Ep01 = E01 - Ea01;                                            \
    const float Ep10 = E10 - Ea10;                                            \
    const float Ep11 = E11 - Ea11;                                            \
    const float mE00 = (m00 * Ep00 + m01 * Ep10) + (Ep00 * m00 + Ep01 * m10); \
    const float mE01 = (m00 * Ep01 + m01 * Ep11) + (Ep00 * m01 + Ep01 * m11); \
    const float mE10 = (m10 * Ep00 + m11 * Ep10) + (Ep10 * m00 + Ep11 * m10); \
    const float mE11 = (m10 * Ep01 + m11 * Ep11) + (Ep10 * m01 + Ep11 * m11); \
    const float divv = gv00 + gv11;                                           \
    const float cdot =                                                        \
        -(v0 * dY_c + v1 * dX_c) - cad0 * c + cad1 * c * divv + cad2 * g;     \
    const float md00 = -(v0 * dY_m00 + v1 * dX_m00) - ww * m10 - ww * m01 -   \
                       my0 * m00 + my1 * mE00 - my2 * c * mE00 + my3 * trm +  \
                       my4 * trm * m00;                                       \
    const float md01 = -(v0 * dY_m01 + v1 * dX_m01) - ww * m11 + ww * m00 -   \
                       my0 * m01 + my1 * mE01 - my2 * c * mE01 +              \
                       my4 * trm * m01;                                       \
    const float md10 = -(v0 * dY_m10 + v1 * dX_m10) + ww * m00 - ww * m11 -   \
                       my0 * m10 + my1 * mE10 - my2 * c * mE10 +              \
                       my4 * trm * m10;                                       \
    const float md11 = -(v0 * dY_m11 + v1 * dX_m11) + ww * m01 + ww * m10 -   \
                       my0 * m11 + my1 * mE11 - my2 * c * mE11 +              \
                       my4 * trm * m11;                                       \
    out[idx] = md00;                                                          \
    out[idx + (size_t)NHW] = md01;                                            \
    out[idx + 2 * (size_t)NHW] = md10;                                        \
    out[idx + 3 * (size_t)NHW] = md11;                                        \
    out[idx + 4 * (size_t)NHW] = cdot;                                        \
  }

  POINT(0) POINT(1) POINT(2) POINT(3)
  POINT(4) POINT(5) POINT(6) POINT(7)
#undef POINT
}

extern "C" void kernel_launch(void* const* d_in, const int* in_sizes, int n_in,
                              void* d_out, int out_size, void* d_ws, size_t ws_size,
                              hipStream_t stream) {
  (void)in_sizes; (void)n_in; (void)out_size; (void)ws_size;
  const float* y = (const float*)d_in[0];
  const float* v = (const float*)d_in[1];
  const float* gds = (const float*)d_in[2];
  const float* cadc = (const float*)d_in[3];
  const float* myoc = (const float*)d_in[4];
  float* out = (float*)d_out;

  double* acc = (double*)d_ws;                       // 8B accumulator
  float* planes = (float*)((char*)d_ws + 512);       // 14 x NHW fp32 planes (7..13 used)

  hipMemsetAsync(acc, 0, sizeof(double), stream);
  k_dx<<<dim3(NH, 7), dim3(256), 0, stream>>>(y, v, planes, acc);
  k_dyf<<<dim3(NW / TW, NH / TH), dim3(512), 0, stream>>>(y, v, gds, cadc, myoc,
                                                          planes, acc, out);
}